// Round 6
// baseline (319.536 us; speedup 1.0000x reference)
//
#include <hip/hip_runtime.h>
#include <stdint.h>

// Problem constants
#define NB   4
#define SLEN 2048
#define EMB  1024
#define NH   16
#define HD   64
#define MTOT (NB * SLEN)   // 8192

typedef __bf16 bf8_t  __attribute__((ext_vector_type(8)));
typedef __bf16 bf4_t  __attribute__((ext_vector_type(4)));
typedef float  f4_t   __attribute__((ext_vector_type(4)));
typedef unsigned int u32x2 __attribute__((ext_vector_type(2)));
typedef unsigned int u32x4 __attribute__((ext_vector_type(4)));

#if __has_builtin(__builtin_amdgcn_exp2f)
#define EXP2(x) __builtin_amdgcn_exp2f(x)
#else
#define EXP2(x) exp2f(x)
#endif

__device__ __forceinline__ void gld16(const void* g, void* l) {
    __builtin_amdgcn_global_load_lds(
        (__attribute__((address_space(1))) void*)(g),
        (__attribute__((address_space(3))) void*)(l),
        16, 0, 0);
}

// pack two fp32 -> bf16x2, round-to-nearest-ties-away: 2 add + 1 perm
__device__ __forceinline__ uint32_t pack_bf16_rtn(float a, float b) {
    uint32_t ua = __builtin_bit_cast(uint32_t, a) + 0x8000u;
    uint32_t ub = __builtin_bit_cast(uint32_t, b) + 0x8000u;
    return __builtin_amdgcn_perm(ub, ua, 0x07060302u);
}
// pack two fp32 -> bf16x2, truncate (RTZ): 1 perm. Bias cancels in p/sum(p).
__device__ __forceinline__ uint32_t pack_bf16_rtz(float a, float b) {
    return __builtin_amdgcn_perm(__builtin_bit_cast(uint32_t, b),
                                 __builtin_bit_cast(uint32_t, a), 0x07060302u);
}

// ---------------------------------------------------------------- fused cast fp32->bf16
// grid.x = 12288: blocks [0,8192) -> x; [8192,12288) -> 4 weights.
// Wq is pre-scaled by 1/sqrt(D)*log2(e) so attn consumes Q directly (exp2 path).
__global__ __launch_bounds__(256) void cast_all(const float* __restrict__ x,
                                                const float* __restrict__ Wq,
                                                const float* __restrict__ Wk,
                                                const float* __restrict__ Wv,
                                                const float* __restrict__ Wo,
                                                __bf16* __restrict__ xb,
                                                __bf16* __restrict__ wb) {
    int b = blockIdx.x;
    const float* s;
    __bf16* d;
    float sc = 1.0f;
    if (b < 8192) {
        s = x; d = xb;
    } else {
        int y = (b - 8192) >> 10;   // 1024 blocks per weight matrix
        s = (y == 0) ? Wq : (y == 1) ? Wk : (y == 2) ? Wv : Wo;
        d = wb + (size_t)y * (EMB * EMB);
        b = (b - 8192) & 1023;
        if (y == 0) sc = 0.125f * 1.44269504f;  // QSCALE folded into Wq
    }
    int i = (b * 256 + (int)threadIdx.x) * 4;
    float4 f = *(const float4*)(s + i);
    bf4_t o = { (__bf16)(f.x * sc), (__bf16)(f.y * sc),
                (__bf16)(f.z * sc), (__bf16)(f.w * sc) };
    *(bf4_t*)(d + i) = o;
}

// ---------------------------------------------------------------- GEMM building blocks
// stage one 128x64 tile pair (A rows m0.., B rows n0..) into As/Bs, XOR-swizzled
__device__ __forceinline__ void gstage(const __bf16* __restrict__ A,
                                       const __bf16* __restrict__ B,
                                       int m0, int n0, int k0, int K, int tid,
                                       __bf16* __restrict__ As,
                                       __bf16* __restrict__ Bs) {
#pragma unroll
    for (int t = 0; t < 4; ++t) {
        int c   = t * 256 + tid;
        int row = c >> 3;
        int kc  = (c & 7) ^ (row & 7);
        int cb  = c & ~63;  // wave-uniform LDS chunk base
        gld16(A + (size_t)(m0 + row) * K + k0 + kc * 8, As + cb * 8);
        gld16(B + (size_t)(n0 + row) * K + k0 + kc * 8, Bs + cb * 8);
    }
}

// one 64-K tile of MFMA work. SWAP: D rows = n (B side), cols = m -> packable rows.
template <bool SWAP>
__device__ __forceinline__ void gcompute(const __bf16* __restrict__ As,
                                         const __bf16* __restrict__ Bs,
                                         f4_t (*acc)[4],
                                         int wm, int wn, int quad, int l16) {
#pragma unroll
    for (int ks = 0; ks < 2; ++ks) {
        bf8_t af[4], bfr[4];
#pragma unroll
        for (int i = 0; i < 4; ++i) {
            int r = wm + i * 16 + l16;
            af[i] = *(const bf8_t*)&As[r * 64 + (((ks * 4 + quad) ^ (r & 7)) * 8)];
        }
#pragma unroll
        for (int j = 0; j < 4; ++j) {
            int r = wn + j * 16 + l16;
            bfr[j] = *(const bf8_t*)&Bs[r * 64 + (((ks * 4 + quad) ^ (r & 7)) * 8)];
        }
#pragma unroll
        for (int i = 0; i < 4; ++i)
#pragma unroll
            for (int j = 0; j < 4; ++j) {
                if (SWAP)
                    acc[i][j] = __builtin_amdgcn_mfma_f32_16x16x32_bf16(
                        bfr[j], af[i], acc[i][j], 0, 0, 0);
                else
                    acc[i][j] = __builtin_amdgcn_mfma_f32_16x16x32_bf16(
                        af[i], bfr[j], acc[i][j], 0, 0, 0);
            }
    }
}

// double-buffered K-loop. Straight-line body (in-loop branches cost -4%, R4).
// Last double-iteration PEELED so the tail does no redundant stage.
template <bool SWAP>
__device__ __forceinline__ void gkloop(const __bf16* __restrict__ A,
                                       const __bf16* __restrict__ B,
                                       int m0, int n0, int K, int tid,
                                       __bf16* As0, __bf16* Bs0,
                                       __bf16* As1, __bf16* Bs1,
                                       f4_t (*acc)[4],
                                       int wm, int wn, int quad, int l16) {
    gstage(A, B, m0, n0, 0, K, tid, As0, Bs0);
    int k0 = 0;
    for (; k0 + 128 < K; k0 += 128) {
        __syncthreads();  // drains prefetch into buf0; all waves done with buf1
        gstage(A, B, m0, n0, k0 + 64, K, tid, As1, Bs1);
        gcompute<SWAP>(As0, Bs0, acc, wm, wn, quad, l16);
        __syncthreads();
        gstage(A, B, m0, n0, k0 + 128, K, tid, As0, Bs0);
        gcompute<SWAP>(As1, Bs1, acc, wm, wn, quad, l16);
    }
    // peeled tail: tiles k0 and k0+64 (buf0 already staged)
    __syncthreads();
    gstage(A, B, m0, n0, k0 + 64, K, tid, As1, Bs1);
    gcompute<SWAP>(As0, Bs0, acc, wm, wn, quad, l16);
    __syncthreads();
    gcompute<SWAP>(As1, Bs1, acc, wm, wn, quad, l16);
}

// ---------------------------------------------------------------- fused QKV projection
// grid 1536 (1-D). XCD-bijective swizzle (T1): each XCD gets 192 consecutive
// logical tiles = 3 full B-panel columns resident in its private L2
// (vs 24-panel churn with round-robin). nwg%8==0 -> simple bijective form.
// n0 < 2048 (QK): SWAPPED operands -> lane holds 4 consecutive cols -> b64 stores.
// n0 >= 2048 (V): original order -> 4 consecutive m -> b64 stores into vtb.
__global__ __launch_bounds__(256, 2) void proj_qkv(const __bf16* __restrict__ A,
                                                   const __bf16* __restrict__ B,
                                                   __bf16* __restrict__ qb) {
    __shared__ __bf16 As0[128 * 64], Bs0[128 * 64];
    __shared__ __bf16 As1[128 * 64], Bs1[128 * 64];

    const int tid  = threadIdx.x;
    const int lane = tid & 63;
    const int w    = tid >> 6;
    const int quad = lane >> 4;
    const int l16  = lane & 15;
    const int lin  = blockIdx.x;
    const int sl   = (lin & 7) * 192 + (lin >> 3);   // XCD-contiguous logical id
    const int m0   = (sl & 63) * 128;
    const int n0   = (sl >> 6) * 128;
    const int wm   = (w >> 1) * 64;
    const int wn   = (w & 1) * 64;

    f4_t acc[4][4];
#pragma unroll
    for (int i = 0; i < 4; ++i)
#pragma unroll
        for (int j = 0; j < 4; ++j) acc[i][j] = (f4_t){0.f, 0.f, 0.f, 0.f};

    if (n0 < 2048) {
        gkloop<true>(A, B, m0, n0, EMB, tid, As0, Bs0, As1, Bs1, acc, wm, wn, quad, l16);
#pragma unroll
        for (int i = 0; i < 4; ++i)
#pragma unroll
            for (int j = 0; j < 4; ++j) {
                int m   = m0 + wm + i * 16 + l16;
                int col = n0 + wn + j * 16 + quad * 4;
                __bf16* dst = (col < 1024) ? qb : qb + (size_t)8 * 1024 * 1024;
                bf4_t pk = { (__bf16)acc[i][j][0], (__bf16)acc[i][j][1],
                             (__bf16)acc[i][j][2], (__bf16)acc[i][j][3] };
                *(bf4_t*)&dst[(size_t)m * 1024 + (col & 1023)] = pk;
            }
    } else {
        gkloop<false>(A, B, m0, n0, EMB, tid, As0, Bs0, As1, Bs1, acc, wm, wn, quad, l16);
        __bf16* vtb = qb + (size_t)16 * 1024 * 1024;
#pragma unroll
        for (int i = 0; i < 4; ++i)
#pragma unroll
            for (int j = 0; j < 4; ++j) {
                int m  = m0 + wm + i * 16 + quad * 4;
                int ch = n0 - 2048 + wn + j * 16 + l16;
                size_t idx = ((size_t)(m >> 11) * 1024 + ch) * 2048 + (m & 2047);
                bf4_t pk = { (__bf16)acc[i][j][0], (__bf16)acc[i][j][1],
                             (__bf16)acc[i][j][2], (__bf16)acc[i][j][3] };
                *(bf4_t*)&vtb[idx] = pk;  // 4 consecutive s positions
            }
    }
}

// ---------------------------------------------------------------- output GEMM (fp32 + bias)
// grid 512 (1-D), same XCD-bijective swizzle: 64 logical tiles per XCD = one
// B-panel (256 KB) resident per XCD L2.
__global__ __launch_bounds__(256, 2) void gemm_out(const __bf16* __restrict__ A,
                                                   const __bf16* __restrict__ B,
                                                   float* __restrict__ C,
                                                   const float* __restrict__ bias) {
    __shared__ __bf16 As0[128 * 64], Bs0[128 * 64];
    __shared__ __bf16 As1[128 * 64], Bs1[128 * 64];

    const int tid  = threadIdx.x;
    const int lane = tid & 63;
    const int w    = tid >> 6;
    const int quad = lane >> 4;
    const int l16  = lane & 15;
    const int lin  = blockIdx.x;
    const int sl   = (lin & 7) * 64 + (lin >> 3);
    const int m0   = (sl & 63) * 128;
    const int n0   = (sl >> 6) * 128;
    const int wm   = (w >> 1) * 64;
    const int wn   = (w & 1) * 64;

    f4_t acc[4][4];
#pragma unroll
    for (int i = 0; i < 4; ++i)
#pragma unroll
        for (int j = 0; j < 4; ++j) acc[i][j] = (f4_t){0.f, 0.f, 0.f, 0.f};

    gkloop<true>(A, B, m0, n0, EMB, tid, As0, Bs0, As1, Bs1, acc, wm, wn, quad, l16);

#pragma unroll
    for (int i = 0; i < 4; ++i)
#pragma unroll
        for (int j = 0; j < 4; ++j) {
            int m   = m0 + wm + i * 16 + l16;
            int col = n0 + wn + j * 16 + quad * 4;
            float4 bv = *(const float4*)&bias[col];
            float4 ov = { acc[i][j][0] + bv.x, acc[i][j][1] + bv.y,
                          acc[i][j][2] + bv.z, acc[i][j][3] + bv.w };
            *(float4*)&C[(size_t)m * EMB + col] = ov;
        }
}

// ---------------------------------------------------------------- flash attention helpers
// K-only staging (V is read directly from L2 — per-head K/V is 512 KB and all
// q-blocks of a head sit on one XCD, so V^T is L2-resident; catalog #7: staging
// L2-fit data is pure overhead). 512 threads stage one 64x64 K tile (16B each).
__device__ __forceinline__ void attn_stage(const __bf16* __restrict__ kbase,
                                           int l0, int tid,
                                           __bf16* __restrict__ Ksb) {
    int c   = tid;                   // 0..511 chunks of 8 bf16
    int row = c >> 3;
    int kc  = (c & 7) ^ (row & 7);   // XOR swizzle
    int cb  = c & ~63;               // wave-uniform chunk base
    gld16(kbase + (size_t)(l0 + row) * EMB + kc * 8, Ksb + cb * 8);
}

// ---- half-tile (32 keys) building blocks for the rolling pipeline ----
// QK^T + exp2 + RTZ pack for keys [ks*32, ks*32+32) of one 64-key K tile.
// pk[jq][jkl*2+h]: keys 16*(ks*2+jkl) + 4*quad + 2*h + {0,1}, q-col = l16.
__device__ __forceinline__ void qkexp_half(const __bf16* __restrict__ Ksb, int ks,
                                           const bf8_t (*bq)[2],
                                           uint32_t (*pk)[4],
                                           int quad, int l16, int sw) {
#pragma unroll
    for (int jkl = 0; jkl < 2; ++jkl) {
        const int jk = ks * 2 + jkl;
        bf8_t ak0 = *(const bf8_t*)&Ksb[(jk * 16 + l16) * 64 + ((quad ^ sw) * 8)];
        bf8_t ak1 = *(const bf8_t*)&Ksb[(jk * 16 + l16) * 64 + (((4 + quad) ^ sw) * 8)];
#pragma unroll
        for (int jq = 0; jq < 2; ++jq) {
            f4_t e = (f4_t){0.f, 0.f, 0.f, 0.f};
            e = __builtin_amdgcn_mfma_f32_16x16x32_bf16(ak0, bq[jq][0], e, 0, 0, 0);
            e = __builtin_amdgcn_mfma_f32_16x16x32_bf16(ak1, bq[jq][1], e, 0, 0, 0);
            pk[jq][jkl * 2 + 0] = pack_bf16_rtz(EXP2(e[0]), EXP2(e[1]));
            pk[jq][jkl * 2 + 1] = pack_bf16_rtz(EXP2(e[2]), EXP2(e[3]));
        }
    }
}

// permlane quad-exchange -> B-operand fragments, then PV + denominator for the
// same 32-key half. V fragments come straight from global (L2): old staged read
// was V^T[d = jd*16+l16][l0 + (ks*4+quad)*8 + 0..7]; the direct read
// vpl0 + ks*32 + quad*8 + jd*16*SLEN (vpl0 = vbase + l16*SLEN + quad*8 + l0)
// yields the identical values. Per instruction: 16 rows x 64B full cache lines
// (128B-aligned) -> line-coalesced. Loads issued before the permlane block so
// the exchange + ls-MFMA covers most of the ~200cy L2 latency.
__device__ __forceinline__ void pv_half(const __bf16* __restrict__ vpl0, int ks,
                                        const uint32_t (*pk)[4], bf8_t aones,
                                        f4_t* ls, f4_t (*o)[4]) {
    bf8_t av[4];
#pragma unroll
    for (int jd = 0; jd < 4; ++jd)
        av[jd] = *(const bf8_t*)(vpl0 + ks * 32 + (size_t)jd * 16 * SLEN);
    bf8_t bp[2];
#pragma unroll
    for (int jq = 0; jq < 2; ++jq) {
        u32x2 s0 = __builtin_amdgcn_permlane32_swap(pk[jq][0], pk[jq][2], false, false);
        u32x2 s1 = __builtin_amdgcn_permlane32_swap(pk[jq][1], pk[jq][3], false, false);
        u32x2 t0 = __builtin_amdgcn_permlane16_swap(s0[0], s0[1], false, false);
        u32x2 t1 = __builtin_amdgcn_permlane16_swap(s1[0], s1[1], false, false);
        bp[jq] = __builtin_bit_cast(bf8_t, (u32x4){t0[0], t1[0], t0[1], t1[1]});
    }
    __builtin_amdgcn_s_setprio(1);
#pragma unroll
    for (int jq = 0; jq < 2; ++jq)
        ls[jq] = __builtin_amdgcn_mfma_f32_16x16x32_bf16(aones, bp[jq], ls[jq], 0, 0, 0);
#pragma unroll
    for (int jd = 0; jd < 4; ++jd)
#pragma unroll
        for (int jq = 0; jq < 2; ++jq)
            o[jq][jd] = __builtin_amdgcn_mfma_f32_16x16x32_bf16(av[jd], bp[jq],
                                                                o[jq][jd], 0, 0, 0);
    __builtin_amdgcn_s_setprio(0);
}

// one 128-key pair (K tiles Ka,Kb; V keys L..L+127 direct from L2), rolling
// 2-stage pipeline over 4 half-tiles: QKexp(h+1) adjacent to PV(h) so QK-MFMAs
// co-schedule with the previous half's exp2/pack/permlane VALU work.
__device__ __forceinline__ void attn_pair(const __bf16* __restrict__ Ka,
                                          const __bf16* __restrict__ Kb,
                                          const __bf16* __restrict__ vgl, int L,
                                          const bf8_t (*bq)[2], bf8_t aones,
                                          f4_t* ls, f4_t (*o)[4],
                                          int quad, int l16, int sw) {
    uint32_t pkA[2][4], pkB[2][4];
    qkexp_half(Ka, 0, bq, pkA, quad, l16, sw);                 // h0 (bubble head)
    qkexp_half(Ka, 1, bq, pkB, quad, l16, sw);                 // h1 QK
    pv_half(vgl + L, 0, pkA, aones, ls, o);                    //  ∥ h0 PV
    qkexp_half(Kb, 0, bq, pkA, quad, l16, sw);                 // h2 QK
    pv_half(vgl + L, 1, pkB, aones, ls, o);                    //  ∥ h1 PV
    qkexp_half(Kb, 1, bq, pkB, quad, l16, sw);                 // h3 QK
    pv_half(vgl + L + 64, 0, pkA, aones, ls, o);               //  ∥ h2 PV
    pv_half(vgl + L + 64, 1, pkB, aones, ls, o);               // h3 PV (bubble tail)
}

// ---------------------------------------------------------------- flash attention (fixed-max softmax)
// grid: (NB*NH, S/256). block 512 = 8 waves; wave w owns 32 q rows (2 x 16).
// blockIdx.x = head -> same-head q-blocks co-locate on one XCD (L2 K/V reuse).
// K pair-slot double buffered in LDS (32 KB); V read directly from L2.
// P fully in registers (permlane exchange), rolling half-tile pipeline,
// last iteration peeled (straight-line hot loop).
__global__ __launch_bounds__(512, 4) void attn_fwd(const __bf16* __restrict__ Q,
                                                   const __bf16* __restrict__ K,
                                                   const __bf16* __restrict__ Vt,
                                                   __bf16* __restrict__ O) {
    __shared__ __bf16 Ks0[64 * 64], Ks1[64 * 64];   // slot0: keys L..L+127
    __shared__ __bf16 Ks2[64 * 64], Ks3[64 * 64];   // slot1: keys L+128..L+255

    const int tid  = threadIdx.x;
    const int lane = tid & 63;
    const int w    = tid >> 6;        // 0..7
    const int quad = lane >> 4;
    const int l16  = lane & 15;
    const int nh   = blockIdx.x;
    const int n    = nh >> 4;
    const int h    = nh & 15;
    const int q0   = blockIdx.y * 256 + w * 32;   // this wave's first q row

    // Q fragments (B-operand layout: n=l16 -> q row q0+jq*16+l16, k=quad*8+j -> d)
    // QSCALE*log2(e) already folded into Wq at cast time -> plain loads.
    bf8_t bq[2][2];  // [jq][ks]
#pragma unroll
    for (int jq = 0; jq < 2; ++jq)
#pragma unroll
        for (int ks = 0; ks < 2; ++ks)
            bq[jq][ks] = *(const bf8_t*)(Q + (size_t)(n * SLEN + q0 + jq * 16 + l16) * EMB +
                                         h * HD + ks * 32 + quad * 8);

    bf8_t aones;
#pragma unroll
    for (int t = 0; t < 8; ++t) aones[t] = (__bf16)1.0f;

    f4_t ls[2];     // denominator accumulator (ones-MFMA; all C rows identical per q)
    f4_t o[2][4];   // [jq][jd]; C-tile row = d = jd*16+quad*4+r, col = q = l16
#pragma unroll
    for (int jq = 0; jq < 2; ++jq) {
        ls[jq] = (f4_t){0.f, 0.f, 0.f, 0.f};
#pragma unroll
        for (int jd = 0; jd < 4; ++jd) o[jq][jd] = (f4_t){0.f, 0.f, 0.f, 0.f};
    }

    const __bf16* kbase  = K + (size_t)n * SLEN * EMB + h * HD;
    const __bf16* vglane = Vt + (size_t)nh * HD * SLEN + (size_t)l16 * SLEN + quad * 8;
    const int sw = l16 & 7;  // XOR swizzle key for K fragment reads

    // prologue: stage K pair 0 into slot0
    attn_stage(kbase, 0, tid, Ks0);
    attn_stage(kbase, 64, tid, Ks1);

    int it = 0;
    for (; it < 14; it += 2) {   // two 128-key pairs per iteration, straight-line
        int L = it * 128;
        __syncthreads();  // drains stage into slot0; all waves done with slot1
        attn_stage(kbase, L + 128, tid, Ks2);
        attn_stage(kbase, L + 192, tid, Ks3);
        attn_pair(Ks0, Ks1, vglane, L, bq, aones, ls, o, quad, l16, sw);
        __syncthreads();  // drains stage into slot1; all waves done with slot0
        attn_stage(kbase, L + 256, tid, Ks0);
        attn_stage(kbase, L + 320, tid, Ks1);
        attn_pair(Ks2, Ks3, vglane, L + 128, bq, aones, ls, o, quad, l16, sw);
    }
    // peeled tail: pairs 14 (slot0, already staged) and 15 (staged here)
    {
        int L = it * 128;  // 1792
        __syncthreads();
        attn_stage(kbase, L + 128, tid, Ks2);
        attn_stage(kbase, L + 192, tid, Ks3);
        attn_pair(Ks0, Ks1, vglane, L, bq, aones, ls, o, quad, l16, sw);
        __syncthreads();
        attn_pair(Ks2, Ks3, vglane, L + 128, bq, aones, ls, o, quad, l16, sw);
    }

    // epilogue: normalize, RTN pack, store. q row = q0+jq*16+l16, d = jd*16+quad*4+r
#pragma unroll
    for (int jq = 0; jq < 2; ++jq) {
        float inv = 1.0f / ls[jq][0];
#pragma unroll
        for (int jd = 0; jd < 4; ++jd) {
            uint32_t d0 = pack_bf16_rtn(o[jq][jd][0] * inv, o[jq][jd][1] * inv);
            uint32_t d1 = pack_bf16_rtn(o[jq][jd][2] * inv, o[jq][jd][3] * inv);
            *(uint2*)&O[(size_t)(n * SLEN + q0 + jq * 16 + l16) * EMB + h * HD +
                        jd * 16 + quad * 4] = (uint2){d0, d1};
        }
    }
}

// ---------------------------------------------------------------- launch
extern "C" void kernel_launch(void* const* d_in, const int* in_sizes, int n_in,
                              void* d_out, int out_size, void* d_ws, size_t ws_size,
                              hipStream_t stream) {
    const float* x  = (const float*)d_in[0];
    const float* Wq = (const float*)d_in[1];
    const float* Wk = (const float*)d_in[2];
    const float* Wv = (const float*)d_in[3];
    const float* Wo = (const float*)d_in[4];
    const float* bo = (const float*)d_in[5];

    // Workspace layout (72 MB; ab aliases xb — x dead after projections).
    // wqb.. contiguous [Wq|Wk|Wv|Wo] bf16; qb/kb/vtb contiguous at 16MB strides.
    char* wsb = (char*)d_ws;
    const size_t MB = (size_t)1 << 20;
    __bf16* xb  = (__bf16*)(wsb + 0 * MB);    // 16 MB  [8192][1024]
    __bf16* ab  = xb;                         // alias
    __bf16* wqb = (__bf16*)(wsb + 16 * MB);   // 2 MB each, contiguous
    __bf16* wob = (__bf16*)(wsb + 22 * MB);
    __bf16* qb  = (__bf16*)(wsb + 24 * MB);   // 16 MB
    __bf16* kb  = (__bf16*)(wsb + 40 * MB);   // 16 MB
    __bf16* vtb = (__bf16*)(wsb + 56 * MB);   // 16 MB  [nh*64+d][2048]

    cast_all<<<dim3(12288), dim3(256), 0, stream>>>(x, Wq, Wk, Wv, Wo, xb, wqb);

    // fused QKV projection: 1536 blocks (6/CU), dbuf K-loop, XCD-swizzled grid
    proj_qkv<<<dim3(1536), 256, 0, stream>>>(xb, wqb, qb);

    // heads on grid.x -> same-head q-blocks co-locate on one XCD (L2 K/V reuse)
    attn_fwd<<<dim3(NB * NH, SLEN / 256), 512, 0, stream>>>(qb, kb, vtb, ab);

    gemm_out<<<dim3(512), 256, 0, stream>>>(ab, wob, (float*)d_out, bo);
}

// Round 7
// 261.289 us; speedup vs baseline: 1.2229x; 1.2229x over previous
//
#include <hip/hip_runtime.h>
#include <stdint.h>

// Problem constants
#define NB   4
#define SLEN 2048
#define EMB  1024
#define NH   16
#define HD   64
#define MTOT (NB * SLEN)   // 8192

typedef __bf16 bf8_t  __attribute__((ext_vector_type(8)));
typedef __bf16 bf4_t  __attribute__((ext_vector_type(4)));
typedef float  f4_t   __attribute__((ext_vector_type(4)));
typedef unsigned int u32x2 __attribute__((ext_vector_type(2)));
typedef unsigned int u32x4 __attribute__((ext_vector_type(4)));

#if __has_builtin(__builtin_amdgcn_exp2f)
#define EXP2(x) __builtin_amdgcn_exp2f(x)
#else
#define EXP2(x) exp2f(x)
#endif

__device__ __forceinline__ void gld16(const void* g, void* l) {
    __builtin_amdgcn_global_load_lds(
        (__attribute__((address_space(1))) void*)(g),
        (__attribute__((address_space(3))) void*)(l),
        16, 0, 0);
}

// pack two fp32 -> bf16x2, round-to-nearest-ties-away: 2 add + 1 perm
__device__ __forceinline__ uint32_t pack_bf16_rtn(float a, float b) {
    uint32_t ua = __builtin_bit_cast(uint32_t, a) + 0x8000u;
    uint32_t ub = __builtin_bit_cast(uint32_t, b) + 0x8000u;
    return __builtin_amdgcn_perm(ub, ua, 0x07060302u);
}
// pack two fp32 -> bf16x2, truncate (RTZ): 1 perm. Bias cancels in p/sum(p).
__device__ __forceinline__ uint32_t pack_bf16_rtz(float a, float b) {
    return __builtin_amdgcn_perm(__builtin_bit_cast(uint32_t, b),
                                 __builtin_bit_cast(uint32_t, a), 0x07060302u);
}

// ---------------------------------------------------------------- fused cast fp32->bf16
// grid.x = 12288: blocks [0,8192) -> x; [8192,12288) -> 4 weights.
// Wq is pre-scaled by 1/sqrt(D)*log2(e) so attn consumes Q directly (exp2 path).
__global__ __launch_bounds__(256) void cast_all(const float* __restrict__ x,
                                                const float* __restrict__ Wq,
                                                const float* __restrict__ Wk,
                                                const float* __restrict__ Wv,
                                                const float* __restrict__ Wo,
                                                __bf16* __restrict__ xb,
                                                __bf16* __restrict__ wb) {
    int b = blockIdx.x;
    const float* s;
    __bf16* d;
    float sc = 1.0f;
    if (b < 8192) {
        s = x; d = xb;
    } else {
        int y = (b - 8192) >> 10;   // 1024 blocks per weight matrix
        s = (y == 0) ? Wq : (y == 1) ? Wk : (y == 2) ? Wv : Wo;
        d = wb + (size_t)y * (EMB * EMB);
        b = (b - 8192) & 1023;
        if (y == 0) sc = 0.125f * 1.44269504f;  // QSCALE folded into Wq
    }
    int i = (b * 256 + (int)threadIdx.x) * 4;
    float4 f = *(const float4*)(s + i);
    bf4_t o = { (__bf16)(f.x * sc), (__bf16)(f.y * sc),
                (__bf16)(f.z * sc), (__bf16)(f.w * sc) };
    *(bf4_t*)(d + i) = o;
}

// ---------------------------------------------------------------- GEMM building blocks
// stage one 128x64 tile pair (A rows m0.., B rows n0..) into As/Bs, XOR-swizzled
__device__ __forceinline__ void gstage(const __bf16* __restrict__ A,
                                       const __bf16* __restrict__ B,
                                       int m0, int n0, int k0, int K, int tid,
                                       __bf16* __restrict__ As,
                                       __bf16* __restrict__ Bs) {
#pragma unroll
    for (int t = 0; t < 4; ++t) {
        int c   = t * 256 + tid;
        int row = c >> 3;
        int kc  = (c & 7) ^ (row & 7);
        int cb  = c & ~63;  // wave-uniform LDS chunk base
        gld16(A + (size_t)(m0 + row) * K + k0 + kc * 8, As + cb * 8);
        gld16(B + (size_t)(n0 + row) * K + k0 + kc * 8, Bs + cb * 8);
    }
}

// one 64-K tile of MFMA work. SWAP: D rows = n (B side), cols = m -> packable rows.
template <bool SWAP>
__device__ __forceinline__ void gcompute(const __bf16* __restrict__ As,
                                         const __bf16* __restrict__ Bs,
                                         f4_t (*acc)[4],
                                         int wm, int wn, int quad, int l16) {
#pragma unroll
    for (int ks = 0; ks < 2; ++ks) {
        bf8_t af[4], bfr[4];
#pragma unroll
        for (int i = 0; i < 4; ++i) {
            int r = wm + i * 16 + l16;
            af[i] = *(const bf8_t*)&As[r * 64 + (((ks * 4 + quad) ^ (r & 7)) * 8)];
        }
#pragma unroll
        for (int j = 0; j < 4; ++j) {
            int r = wn + j * 16 + l16;
            bfr[j] = *(const bf8_t*)&Bs[r * 64 + (((ks * 4 + quad) ^ (r & 7)) * 8)];
        }
#pragma unroll
        for (int i = 0; i < 4; ++i)
#pragma unroll
            for (int j = 0; j < 4; ++j) {
                if (SWAP)
                    acc[i][j] = __builtin_amdgcn_mfma_f32_16x16x32_bf16(
                        bfr[j], af[i], acc[i][j], 0, 0, 0);
                else
                    acc[i][j] = __builtin_amdgcn_mfma_f32_16x16x32_bf16(
                        af[i], bfr[j], acc[i][j], 0, 0, 0);
            }
    }
}

// double-buffered K-loop. Straight-line body (in-loop branches cost -4%, R4).
// Last double-iteration PEELED so the tail does no redundant stage.
template <bool SWAP>
__device__ __forceinline__ void gkloop(const __bf16* __restrict__ A,
                                       const __bf16* __restrict__ B,
                                       int m0, int n0, int K, int tid,
                                       __bf16* As0, __bf16* Bs0,
                                       __bf16* As1, __bf16* Bs1,
                                       f4_t (*acc)[4],
                                       int wm, int wn, int quad, int l16) {
    gstage(A, B, m0, n0, 0, K, tid, As0, Bs0);
    int k0 = 0;
    for (; k0 + 128 < K; k0 += 128) {
        __syncthreads();  // drains prefetch into buf0; all waves done with buf1
        gstage(A, B, m0, n0, k0 + 64, K, tid, As1, Bs1);
        gcompute<SWAP>(As0, Bs0, acc, wm, wn, quad, l16);
        __syncthreads();
        gstage(A, B, m0, n0, k0 + 128, K, tid, As0, Bs0);
        gcompute<SWAP>(As1, Bs1, acc, wm, wn, quad, l16);
    }
    // peeled tail: tiles k0 and k0+64 (buf0 already staged)
    __syncthreads();
    gstage(A, B, m0, n0, k0 + 64, K, tid, As1, Bs1);
    gcompute<SWAP>(As0, Bs0, acc, wm, wn, quad, l16);
    __syncthreads();
    gcompute<SWAP>(As1, Bs1, acc, wm, wn, quad, l16);
}

// ---------------------------------------------------------------- fused QKV projection
// grid 1536 (1-D). XCD-bijective swizzle (T1): each XCD gets 192 consecutive
// logical tiles = 3 full B-panel columns resident in its private L2.
// n0 < 2048 (QK): SWAPPED operands -> lane holds 4 consecutive cols -> b64 stores.
// n0 >= 2048 (V): original order -> 4 consecutive m -> b64 stores into vtb.
__global__ __launch_bounds__(256, 2) void proj_qkv(const __bf16* __restrict__ A,
                                                   const __bf16* __restrict__ B,
                                                   __bf16* __restrict__ qb) {
    __shared__ __bf16 As0[128 * 64], Bs0[128 * 64];
    __shared__ __bf16 As1[128 * 64], Bs1[128 * 64];

    const int tid  = threadIdx.x;
    const int lane = tid & 63;
    const int w    = tid >> 6;
    const int quad = lane >> 4;
    const int l16  = lane & 15;
    const int lin  = blockIdx.x;
    const int sl   = (lin & 7) * 192 + (lin >> 3);   // XCD-contiguous logical id
    const int m0   = (sl & 63) * 128;
    const int n0   = (sl >> 6) * 128;
    const int wm   = (w >> 1) * 64;
    const int wn   = (w & 1) * 64;

    f4_t acc[4][4];
#pragma unroll
    for (int i = 0; i < 4; ++i)
#pragma unroll
        for (int j = 0; j < 4; ++j) acc[i][j] = (f4_t){0.f, 0.f, 0.f, 0.f};

    if (n0 < 2048) {
        gkloop<true>(A, B, m0, n0, EMB, tid, As0, Bs0, As1, Bs1, acc, wm, wn, quad, l16);
#pragma unroll
        for (int i = 0; i < 4; ++i)
#pragma unroll
            for (int j = 0; j < 4; ++j) {
                int m   = m0 + wm + i * 16 + l16;
                int col = n0 + wn + j * 16 + quad * 4;
                __bf16* dst = (col < 1024) ? qb : qb + (size_t)8 * 1024 * 1024;
                bf4_t pk = { (__bf16)acc[i][j][0], (__bf16)acc[i][j][1],
                             (__bf16)acc[i][j][2], (__bf16)acc[i][j][3] };
                *(bf4_t*)&dst[(size_t)m * 1024 + (col & 1023)] = pk;
            }
    } else {
        gkloop<false>(A, B, m0, n0, EMB, tid, As0, Bs0, As1, Bs1, acc, wm, wn, quad, l16);
        __bf16* vtb = qb + (size_t)16 * 1024 * 1024;
#pragma unroll
        for (int i = 0; i < 4; ++i)
#pragma unroll
            for (int j = 0; j < 4; ++j) {
                int m  = m0 + wm + i * 16 + quad * 4;
                int ch = n0 - 2048 + wn + j * 16 + l16;
                size_t idx = ((size_t)(m >> 11) * 1024 + ch) * 2048 + (m & 2047);
                bf4_t pk = { (__bf16)acc[i][j][0], (__bf16)acc[i][j][1],
                             (__bf16)acc[i][j][2], (__bf16)acc[i][j][3] };
                *(bf4_t*)&vtb[idx] = pk;  // 4 consecutive s positions
            }
    }
}

// ---------------------------------------------------------------- output GEMM (fp32 + bias)
// grid 512 (1-D), same XCD-bijective swizzle: 64 logical tiles per XCD = one
// B-panel (256 KB) resident per XCD L2.
__global__ __launch_bounds__(256, 2) void gemm_out(const __bf16* __restrict__ A,
                                                   const __bf16* __restrict__ B,
                                                   float* __restrict__ C,
                                                   const float* __restrict__ bias) {
    __shared__ __bf16 As0[128 * 64], Bs0[128 * 64];
    __shared__ __bf16 As1[128 * 64], Bs1[128 * 64];

    const int tid  = threadIdx.x;
    const int lane = tid & 63;
    const int w    = tid >> 6;
    const int quad = lane >> 4;
    const int l16  = lane & 15;
    const int lin  = blockIdx.x;
    const int sl   = (lin & 7) * 64 + (lin >> 3);
    const int m0   = (sl & 63) * 128;
    const int n0   = (sl >> 6) * 128;
    const int wm   = (w >> 1) * 64;
    const int wn   = (w & 1) * 64;

    f4_t acc[4][4];
#pragma unroll
    for (int i = 0; i < 4; ++i)
#pragma unroll
        for (int j = 0; j < 4; ++j) acc[i][j] = (f4_t){0.f, 0.f, 0.f, 0.f};

    gkloop<true>(A, B, m0, n0, EMB, tid, As0, Bs0, As1, Bs1, acc, wm, wn, quad, l16);

#pragma unroll
    for (int i = 0; i < 4; ++i)
#pragma unroll
        for (int j = 0; j < 4; ++j) {
            int m   = m0 + wm + i * 16 + l16;
            int col = n0 + wn + j * 16 + quad * 4;
            float4 bv = *(const float4*)&bias[col];
            float4 ov = { acc[i][j][0] + bv.x, acc[i][j][1] + bv.y,
                          acc[i][j][2] + bv.z, acc[i][j][3] + bv.w };
            *(float4*)&C[(size_t)m * EMB + col] = ov;
        }
}

// ---------------------------------------------------------------- flash attention helpers
// 512-thread staging: each thread stages one 16B chunk of a 64-key K tile and
// one of the matching V tile. (V MUST be LDS-staged: direct-global V reads
// share the ordered vmcnt counter with global_load_lds K-prefetch, so every
// V use would drain the K pipeline — measured 74->138 us in round 6.)
__device__ __forceinline__ void attn_stage(const __bf16* __restrict__ kbase,
                                           const __bf16* __restrict__ vbase,
                                           int l0, int tid,
                                           __bf16* __restrict__ Ksb,
                                           __bf16* __restrict__ Vsb) {
    int c   = tid;                   // 0..511 chunks of 8 bf16
    int row = c >> 3;
    int kc  = (c & 7) ^ (row & 7);   // XOR swizzle
    int cb  = c & ~63;               // wave-uniform chunk base
    gld16(kbase + (size_t)(l0 + row) * EMB + kc * 8, Ksb + cb * 8);
    gld16(vbase + (size_t)row * SLEN + l0 + kc * 8, Vsb + cb * 8);
}

// ---- half-tile (32 keys) building blocks for the rolling pipeline ----
// QK^T + exp2 + RTZ pack for keys [ks*32, ks*32+32) of one 64-key K tile.
// pk[jq][jkl*2+h]: keys 16*(ks*2+jkl) + 4*quad + 2*h + {0,1}, q-col = l16.
__device__ __forceinline__ void qkexp_half(const __bf16* __restrict__ Ksb, int ks,
                                           const bf8_t (*bq)[2],
                                           uint32_t (*pk)[4],
                                           int quad, int l16, int sw) {
#pragma unroll
    for (int jkl = 0; jkl < 2; ++jkl) {
        const int jk = ks * 2 + jkl;
        bf8_t ak0 = *(const bf8_t*)&Ksb[(jk * 16 + l16) * 64 + ((quad ^ sw) * 8)];
        bf8_t ak1 = *(const bf8_t*)&Ksb[(jk * 16 + l16) * 64 + (((4 + quad) ^ sw) * 8)];
#pragma unroll
        for (int jq = 0; jq < 2; ++jq) {
            f4_t e = (f4_t){0.f, 0.f, 0.f, 0.f};
            e = __builtin_amdgcn_mfma_f32_16x16x32_bf16(ak0, bq[jq][0], e, 0, 0, 0);
            e = __builtin_amdgcn_mfma_f32_16x16x32_bf16(ak1, bq[jq][1], e, 0, 0, 0);
            pk[jq][jkl * 2 + 0] = pack_bf16_rtz(EXP2(e[0]), EXP2(e[1]));
            pk[jq][jkl * 2 + 1] = pack_bf16_rtz(EXP2(e[2]), EXP2(e[3]));
        }
    }
}

// permlane quad-exchange -> B-operand fragments, then PV + denominator for the
// same 32-key half. Exchange derivation: see round-2 notes (verified).
__device__ __forceinline__ void pv_half(const __bf16* __restrict__ Vsb, int ks,
                                        const uint32_t (*pk)[4], bf8_t aones,
                                        f4_t* ls, f4_t (*o)[4],
                                        int quad, int l16, int sw) {
    bf8_t bp[2];
#pragma unroll
    for (int jq = 0; jq < 2; ++jq) {
        u32x2 s0 = __builtin_amdgcn_permlane32_swap(pk[jq][0], pk[jq][2], false, false);
        u32x2 s1 = __builtin_amdgcn_permlane32_swap(pk[jq][1], pk[jq][3], false, false);
        u32x2 t0 = __builtin_amdgcn_permlane16_swap(s0[0], s0[1], false, false);
        u32x2 t1 = __builtin_amdgcn_permlane16_swap(s1[0], s1[1], false, false);
        bp[jq] = __builtin_bit_cast(bf8_t, (u32x4){t0[0], t1[0], t0[1], t1[1]});
    }
    __builtin_amdgcn_s_setprio(1);
#pragma unroll
    for (int jq = 0; jq < 2; ++jq)
        ls[jq] = __builtin_amdgcn_mfma_f32_16x16x32_bf16(aones, bp[jq], ls[jq], 0, 0, 0);
#pragma unroll
    for (int jd = 0; jd < 4; ++jd) {
        bf8_t av = *(const bf8_t*)&Vsb[(jd * 16 + l16) * 64 +
                                       (((ks * 4 + quad) ^ sw) * 8)];
#pragma unroll
        for (int jq = 0; jq < 2; ++jq)
            o[jq][jd] = __builtin_amdgcn_mfma_f32_16x16x32_bf16(av, bp[jq],
                                                                o[jq][jd], 0, 0, 0);
    }
    __builtin_amdgcn_s_setprio(0);
}

// one 128-key pair (tiles A,B), rolling 2-stage pipeline over 4 half-tiles:
// QKexp(h+1) is placed adjacent to PV(h) so its QK-MFMAs co-schedule with the
// previous half's exp2/pack/permlane VALU work (ping-pong pkA/pkB, static idx).
__device__ __forceinline__ void attn_pair(const __bf16* __restrict__ Ka,
                                          const __bf16* __restrict__ Kb,
                                          const __bf16* __restrict__ Va,
                                          const __bf16* __restrict__ Vb,
                                          const bf8_t (*bq)[2], bf8_t aones,
                                          f4_t* ls, f4_t (*o)[4],
                                          int quad, int l16, int sw) {
    uint32_t pkA[2][4], pkB[2][4];
    qkexp_half(Ka, 0, bq, pkA, quad, l16, sw);                 // h0 (bubble head)
    qkexp_half(Ka, 1, bq, pkB, quad, l16, sw);                 // h1 QK
    pv_half(Va, 0, pkA, aones, ls, o, quad, l16, sw);          //  ∥ h0 PV
    qkexp_half(Kb, 0, bq, pkA, quad, l16, sw);                 // h2 QK
    pv_half(Va, 1, pkB, aones, ls, o, quad, l16, sw);          //  ∥ h1 PV
    qkexp_half(Kb, 1, bq, pkB, quad, l16, sw);                 // h3 QK
    pv_half(Vb, 0, pkA, aones, ls, o, quad, l16, sw);          //  ∥ h2 PV
    pv_half(Vb, 1, pkB, aones, ls, o, quad, l16, sw);          // h3 PV (bubble tail)
}

// ---------------------------------------------------------------- flash attention (fixed-max softmax)
// grid: (NB*NH, S/256). block 512 = 8 waves; wave w owns 32 q rows (2 x 16).
// blockIdx.x = head -> same-head q-blocks co-locate on one XCD (L2 K/V reuse).
// Pair-slot double buffering: 2 slots x (K 16KB + V 16KB) = 64 KB LDS,
// ONE barrier per 128 keys. P fully in registers (permlane exchange) with a
// rolling half-tile pipeline. Last iteration PEELED (straight-line hot loop;
// in-loop branches cost -4%, measured round 4).
// Issue-port ~93% saturated (MfmaUtil 44.6 + VALUBusy 49.4, round 5); exp2 is
// the irreducible VALU cost (1/score). Structural floor ~69 us.
__global__ __launch_bounds__(512, 4) void attn_fwd(const __bf16* __restrict__ Q,
                                                   const __bf16* __restrict__ K,
                                                   const __bf16* __restrict__ Vt,
                                                   __bf16* __restrict__ O) {
    __shared__ __bf16 Ks0[64 * 64], Ks1[64 * 64];   // slot0: keys L..L+127
    __shared__ __bf16 Ks2[64 * 64], Ks3[64 * 64];   // slot1: keys L+128..L+255
    __shared__ __bf16 Vs0[64 * 64], Vs1[64 * 64];
    __shared__ __bf16 Vs2[64 * 64], Vs3[64 * 64];

    const int tid  = threadIdx.x;
    const int lane = tid & 63;
    const int w    = tid >> 6;        // 0..7
    const int quad = lane >> 4;
    const int l16  = lane & 15;
    const int nh   = blockIdx.x;
    const int n    = nh >> 4;
    const int h    = nh & 15;
    const int q0   = blockIdx.y * 256 + w * 32;   // this wave's first q row

    // Q fragments (B-operand layout: n=l16 -> q row q0+jq*16+l16, k=quad*8+j -> d)
    // QSCALE*log2(e) already folded into Wq at cast time -> plain loads.
    bf8_t bq[2][2];  // [jq][ks]
#pragma unroll
    for (int jq = 0; jq < 2; ++jq)
#pragma unroll
        for (int ks = 0; ks < 2; ++ks)
            bq[jq][ks] = *(const bf8_t*)(Q + (size_t)(n * SLEN + q0 + jq * 16 + l16) * EMB +
                                         h * HD + ks * 32 + quad * 8);

    bf8_t aones;
#pragma unroll
    for (int t = 0; t < 8; ++t) aones[t] = (__bf16)1.0f;

    f4_t ls[2];     // denominator accumulator (ones-MFMA; all C rows identical per q)
    f4_t o[2][4];   // [jq][jd]; C-tile row = d = jd*16+quad*4+r, col = q = l16
#pragma unroll
    for (int jq = 0; jq < 2; ++jq) {
        ls[jq] = (f4_t){0.f, 0.f, 0.f, 0.f};
#pragma unroll
        for (int jd = 0; jd < 4; ++jd) o[jq][jd] = (f4_t){0.f, 0.f, 0.f, 0.f};
    }

    const __bf16* kbase = K + (size_t)n * SLEN * EMB + h * HD;
    const __bf16* vbase = Vt + (size_t)nh * HD * SLEN;
    const int sw = l16 & 7;  // XOR swizzle key for fragment reads

    // prologue: stage pair 0 into slot0
    attn_stage(kbase, vbase, 0, tid, Ks0, Vs0);
    attn_stage(kbase, vbase, 64, tid, Ks1, Vs1);

    int it = 0;
    for (; it < 14; it += 2) {   // two 128-key pairs per iteration, straight-line
        int L = it * 128;
        __syncthreads();  // drains stage into slot0; all waves done with slot1
        attn_stage(kbase, vbase, L + 128, tid, Ks2, Vs2);
        attn_stage(kbase, vbase, L + 192, tid, Ks3, Vs3);
        attn_pair(Ks0, Ks1, Vs0, Vs1, bq, aones, ls, o, quad, l16, sw);
        __syncthreads();  // drains stage into slot1; all waves done with slot0
        attn_stage(kbase, vbase, L + 256, tid, Ks0, Vs0);
        attn_stage(kbase, vbase, L + 320, tid, Ks1, Vs1);
        attn_pair(Ks2, Ks3, Vs2, Vs3, bq, aones, ls, o, quad, l16, sw);
    }
    // peeled tail: pairs 14 (slot0, already staged) and 15 (staged here)
    {
        int L = it * 128;  // 1792
        __syncthreads();
        attn_stage(kbase, vbase, L + 128, tid, Ks2, Vs2);
        attn_stage(kbase, vbase, L + 192, tid, Ks3, Vs3);
        attn_pair(Ks0, Ks1, Vs0, Vs1, bq, aones, ls, o, quad, l16, sw);
        __syncthreads();
        attn_pair(Ks2, Ks3, Vs2, Vs3, bq, aones, ls, o, quad, l16, sw);
    }

    // epilogue: normalize, RTN pack, store. q row = q0+jq*16+l16, d = jd*16+quad*4+r
#pragma unroll
    for (int jq = 0; jq < 2; ++jq) {
        float inv = 1.0f / ls[jq][0];
#pragma unroll
        for (int jd = 0; jd < 4; ++jd) {
            uint32_t d0 = pack_bf16_rtn(o[jq][jd][0] * inv, o[jq][jd][1] * inv);
            uint32_t d1 = pack_bf16_rtn(o[jq][jd][2] * inv, o[jq][jd][3] * inv);
            *(uint2*)&O[(size_t)(n * SLEN + q0 + jq * 16 + l16) * EMB + h * HD +
                        jd * 16 + quad * 4] = (uint2){d0, d1};
        }
    }
}

// ---------------------------------------------------------------- launch
extern "C" void kernel_launch(void* const* d_in, const int* in_sizes, int n_in,
                              void* d_out, int out_size, void* d_ws, size_t ws_size,
                              hipStream_t stream) {
    const float* x  = (const float*)d_in[0];
    const float* Wq = (const float*)d_in[1];
    const float* Wk = (const float*)d_in[2];
    const float* Wv = (const float*)d_in[3];
    const float* Wo = (const float*)d_in[4];
    const float* bo = (const float*)d_in[5];

    // Workspace layout (72 MB; ab aliases xb — x dead after projections).
    // wqb.. contiguous [Wq|Wk|Wv|Wo] bf16; qb/kb/vtb contiguous at 16MB strides.
    char* wsb = (char*)d_ws;
    const size_t MB = (size_t)1 << 20;
    __bf16* xb  = (__bf16*)(wsb + 0 * MB);    // 16 MB  [8192][1024]
    __bf16* ab  = xb;                         // alias
    __bf16* wqb = (__bf16*)(wsb + 16 * MB);   // 2 MB each, contiguous
    __bf16* wob = (__bf16*)(wsb + 22 * MB);
    __bf16* qb  = (__bf16*)(wsb + 24 * MB);   // 16 MB
    __bf16* kb  = (__bf16*)(wsb + 40 * MB);   // 16 MB
    __bf16* vtb = (__bf16*)(wsb + 56 * MB);   // 16 MB  [nh*64+d][2048]

    cast_all<<<dim3(12288), dim3(256), 0, stream>>>(x, Wq, Wk, Wv, Wo, xb, wqb);

    // fused QKV projection: 1536 blocks (6/CU), dbuf K-loop, XCD-swizzled grid
    proj_qkv<<<dim3(1536), 256, 0, stream>>>(xb, wqb, qb);

    // heads on grid.x -> same-head q-blocks co-locate on one XCD (L2 K/V reuse)
    attn_fwd<<<dim3(NB * NH, SLEN / 256), 512, 0, stream>>>(qb, kb, vtb, ab);

    gemm_out<<<dim3(512), 256, 0, stream>>>(ab, wob, (float*)d_out, bo);
}

// Round 8
// 238.854 us; speedup vs baseline: 1.3378x; 1.0939x over previous
//
#include <hip/hip_runtime.h>
#include <stdint.h>

// Problem constants
#define NB   4
#define SLEN 2048
#define EMB  1024
#define NH   16
#define HD   64
#define MTOT (NB * SLEN)   // 8192

typedef __bf16 bf8_t  __attribute__((ext_vector_type(8)));
typedef __bf16 bf4_t  __attribute__((ext_vector_type(4)));
typedef float  f4_t   __attribute__((ext_vector_type(4)));
typedef unsigned int u32x2 __attribute__((ext_vector_type(2)));
typedef unsigned int u32x4 __attribute__((ext_vector_type(4)));

#if __has_builtin(__builtin_amdgcn_exp2f)
#define EXP2(x) __builtin_amdgcn_exp2f(x)
#else
#define EXP2(x) exp2f(x)
#endif

__device__ __forceinline__ void gld16(const void* g, void* l) {
    __builtin_amdgcn_global_load_lds(
        (__attribute__((address_space(1))) void*)(g),
        (__attribute__((address_space(3))) void*)(l),
        16, 0, 0);
}

// pack two fp32 -> bf16x2, round-to-nearest-ties-away: 2 add + 1 perm
__device__ __forceinline__ uint32_t pack_bf16_rtn(float a, float b) {
    uint32_t ua = __builtin_bit_cast(uint32_t, a) + 0x8000u;
    uint32_t ub = __builtin_bit_cast(uint32_t, b) + 0x8000u;
    return __builtin_amdgcn_perm(ub, ua, 0x07060302u);
}
// pack two fp32 -> bf16x2, truncate (RTZ): 1 perm. Bias cancels in p/sum(p).
__device__ __forceinline__ uint32_t pack_bf16_rtz(float a, float b) {
    return __builtin_amdgcn_perm(__builtin_bit_cast(uint32_t, b),
                                 __builtin_bit_cast(uint32_t, a), 0x07060302u);
}

// ---------------------------------------------------------------- fused cast fp32->bf16
// grid.x = 12288: blocks [0,8192) -> x; [8192,12288) -> 4 weights.
// Wq is pre-scaled by 1/sqrt(D)*log2(e) so attn consumes Q directly (exp2 path).
__global__ __launch_bounds__(256) void cast_all(const float* __restrict__ x,
                                                const float* __restrict__ Wq,
                                                const float* __restrict__ Wk,
                                                const float* __restrict__ Wv,
                                                const float* __restrict__ Wo,
                                                __bf16* __restrict__ xb,
                                                __bf16* __restrict__ wb) {
    int b = blockIdx.x;
    const float* s;
    __bf16* d;
    float sc = 1.0f;
    if (b < 8192) {
        s = x; d = xb;
    } else {
        int y = (b - 8192) >> 10;   // 1024 blocks per weight matrix
        s = (y == 0) ? Wq : (y == 1) ? Wk : (y == 2) ? Wv : Wo;
        d = wb + (size_t)y * (EMB * EMB);
        b = (b - 8192) & 1023;
        if (y == 0) sc = 0.125f * 1.44269504f;  // QSCALE folded into Wq
    }
    int i = (b * 256 + (int)threadIdx.x) * 4;
    float4 f = *(const float4*)(s + i);
    bf4_t o = { (__bf16)(f.x * sc), (__bf16)(f.y * sc),
                (__bf16)(f.z * sc), (__bf16)(f.w * sc) };
    *(bf4_t*)(d + i) = o;
}

// ---------------------------------------------------------------- GEMM building blocks
// stage one 128x64 tile pair (A rows m0.., B rows n0..) into As/Bs, XOR-swizzled
__device__ __forceinline__ void gstage(const __bf16* __restrict__ A,
                                       const __bf16* __restrict__ B,
                                       int m0, int n0, int k0, int K, int tid,
                                       __bf16* __restrict__ As,
                                       __bf16* __restrict__ Bs) {
#pragma unroll
    for (int t = 0; t < 4; ++t) {
        int c   = t * 256 + tid;
        int row = c >> 3;
        int kc  = (c & 7) ^ (row & 7);
        int cb  = c & ~63;  // wave-uniform LDS chunk base
        gld16(A + (size_t)(m0 + row) * K + k0 + kc * 8, As + cb * 8);
        gld16(B + (size_t)(n0 + row) * K + k0 + kc * 8, Bs + cb * 8);
    }
}

// one 64-K tile of MFMA work. SWAP: D rows = n (B side), cols = m -> packable rows.
template <bool SWAP>
__device__ __forceinline__ void gcompute(const __bf16* __restrict__ As,
                                         const __bf16* __restrict__ Bs,
                                         f4_t (*acc)[4],
                                         int wm, int wn, int quad, int l16) {
#pragma unroll
    for (int ks = 0; ks < 2; ++ks) {
        bf8_t af[4], bfr[4];
#pragma unroll
        for (int i = 0; i < 4; ++i) {
            int r = wm + i * 16 + l16;
            af[i] = *(const bf8_t*)&As[r * 64 + (((ks * 4 + quad) ^ (r & 7)) * 8)];
        }
#pragma unroll
        for (int j = 0; j < 4; ++j) {
            int r = wn + j * 16 + l16;
            bfr[j] = *(const bf8_t*)&Bs[r * 64 + (((ks * 4 + quad) ^ (r & 7)) * 8)];
        }
#pragma unroll
        for (int i = 0; i < 4; ++i)
#pragma unroll
            for (int j = 0; j < 4; ++j) {
                if (SWAP)
                    acc[i][j] = __builtin_amdgcn_mfma_f32_16x16x32_bf16(
                        bfr[j], af[i], acc[i][j], 0, 0, 0);
                else
                    acc[i][j] = __builtin_amdgcn_mfma_f32_16x16x32_bf16(
                        af[i], bfr[j], acc[i][j], 0, 0, 0);
            }
    }
}

// double-buffered K-loop. Straight-line body (in-loop branches cost -4%, R4).
// Last double-iteration PEELED so the tail does no redundant stage.
template <bool SWAP>
__device__ __forceinline__ void gkloop(const __bf16* __restrict__ A,
                                       const __bf16* __restrict__ B,
                                       int m0, int n0, int K, int tid,
                                       __bf16* As0, __bf16* Bs0,
                                       __bf16* As1, __bf16* Bs1,
                                       f4_t (*acc)[4],
                                       int wm, int wn, int quad, int l16) {
    gstage(A, B, m0, n0, 0, K, tid, As0, Bs0);
    int k0 = 0;
    for (; k0 + 128 < K; k0 += 128) {
        __syncthreads();  // drains prefetch into buf0; all waves done with buf1
        gstage(A, B, m0, n0, k0 + 64, K, tid, As1, Bs1);
        gcompute<SWAP>(As0, Bs0, acc, wm, wn, quad, l16);
        __syncthreads();
        gstage(A, B, m0, n0, k0 + 128, K, tid, As0, Bs0);
        gcompute<SWAP>(As1, Bs1, acc, wm, wn, quad, l16);
    }
    // peeled tail: tiles k0 and k0+64 (buf0 already staged)
    __syncthreads();
    gstage(A, B, m0, n0, k0 + 64, K, tid, As1, Bs1);
    gcompute<SWAP>(As0, Bs0, acc, wm, wn, quad, l16);
    __syncthreads();
    gcompute<SWAP>(As1, Bs1, acc, wm, wn, quad, l16);
}

// ---------------------------------------------------------------- fused QKV projection
// grid (64, 24), DEFAULT dispatch order — do NOT XCD-swizzle this kernel:
// round-robin with x=m fastest gives each XCD the same 8 m-tiles across 8
// n-panels -> A(2MB)+B(2MB) = 4MB = L2-fit with 8x A reuse. The "contiguous
// panels per XCD" swizzle (round 6/7) made per-XCD A = 16MB -> L2 thrash, -18us.
// n0 < 2048 (QK): SWAPPED operands -> lane holds 4 consecutive cols -> b64 stores.
// n0 >= 2048 (V): original order -> 4 consecutive m -> b64 stores into vtb.
__global__ __launch_bounds__(256, 2) void proj_qkv(const __bf16* __restrict__ A,
                                                   const __bf16* __restrict__ B,
                                                   __bf16* __restrict__ qb) {
    __shared__ __bf16 As0[128 * 64], Bs0[128 * 64];
    __shared__ __bf16 As1[128 * 64], Bs1[128 * 64];

    const int tid  = threadIdx.x;
    const int lane = tid & 63;
    const int w    = tid >> 6;
    const int quad = lane >> 4;
    const int l16  = lane & 15;
    const int m0   = blockIdx.x * 128;
    const int n0   = blockIdx.y * 128;
    const int wm   = (w >> 1) * 64;
    const int wn   = (w & 1) * 64;

    f4_t acc[4][4];
#pragma unroll
    for (int i = 0; i < 4; ++i)
#pragma unroll
        for (int j = 0; j < 4; ++j) acc[i][j] = (f4_t){0.f, 0.f, 0.f, 0.f};

    if (n0 < 2048) {
        gkloop<true>(A, B, m0, n0, EMB, tid, As0, Bs0, As1, Bs1, acc, wm, wn, quad, l16);
#pragma unroll
        for (int i = 0; i < 4; ++i)
#pragma unroll
            for (int j = 0; j < 4; ++j) {
                int m   = m0 + wm + i * 16 + l16;
                int col = n0 + wn + j * 16 + quad * 4;
                __bf16* dst = (col < 1024) ? qb : qb + (size_t)8 * 1024 * 1024;
                bf4_t pk = { (__bf16)acc[i][j][0], (__bf16)acc[i][j][1],
                             (__bf16)acc[i][j][2], (__bf16)acc[i][j][3] };
                *(bf4_t*)&dst[(size_t)m * 1024 + (col & 1023)] = pk;
            }
    } else {
        gkloop<false>(A, B, m0, n0, EMB, tid, As0, Bs0, As1, Bs1, acc, wm, wn, quad, l16);
        __bf16* vtb = qb + (size_t)16 * 1024 * 1024;
#pragma unroll
        for (int i = 0; i < 4; ++i)
#pragma unroll
            for (int j = 0; j < 4; ++j) {
                int m  = m0 + wm + i * 16 + quad * 4;
                int ch = n0 - 2048 + wn + j * 16 + l16;
                size_t idx = ((size_t)(m >> 11) * 1024 + ch) * 2048 + (m & 2047);
                bf4_t pk = { (__bf16)acc[i][j][0], (__bf16)acc[i][j][1],
                             (__bf16)acc[i][j][2], (__bf16)acc[i][j][3] };
                *(bf4_t*)&vtb[idx] = pk;  // 4 consecutive s positions
            }
    }
}

// ---------------------------------------------------------------- output GEMM (fp32 + bias)
// grid (64, 8), default dispatch (same L2 reasoning as proj_qkv).
__global__ __launch_bounds__(256, 2) void gemm_out(const __bf16* __restrict__ A,
                                                   const __bf16* __restrict__ B,
                                                   float* __restrict__ C,
                                                   const float* __restrict__ bias) {
    __shared__ __bf16 As0[128 * 64], Bs0[128 * 64];
    __shared__ __bf16 As1[128 * 64], Bs1[128 * 64];

    const int tid  = threadIdx.x;
    const int lane = tid & 63;
    const int w    = tid >> 6;
    const int quad = lane >> 4;
    const int l16  = lane & 15;
    const int m0   = blockIdx.x * 128;
    const int n0   = blockIdx.y * 128;
    const int wm   = (w >> 1) * 64;
    const int wn   = (w & 1) * 64;

    f4_t acc[4][4];
#pragma unroll
    for (int i = 0; i < 4; ++i)
#pragma unroll
        for (int j = 0; j < 4; ++j) acc[i][j] = (f4_t){0.f, 0.f, 0.f, 0.f};

    gkloop<true>(A, B, m0, n0, EMB, tid, As0, Bs0, As1, Bs1, acc, wm, wn, quad, l16);

#pragma unroll
    for (int i = 0; i < 4; ++i)
#pragma unroll
        for (int j = 0; j < 4; ++j) {
            int m   = m0 + wm + i * 16 + l16;
            int col = n0 + wn + j * 16 + quad * 4;
            float4 bv = *(const float4*)&bias[col];
            float4 ov = { acc[i][j][0] + bv.x, acc[i][j][1] + bv.y,
                          acc[i][j][2] + bv.z, acc[i][j][3] + bv.w };
            *(float4*)&C[(size_t)m * EMB + col] = ov;
        }
}

// ---------------------------------------------------------------- flash attention helpers
// 512-thread staging: each thread stages one 16B chunk of a 64-key K tile and
// one of the matching V tile. (V MUST be LDS-staged: direct-global V reads
// share the ordered vmcnt counter with global_load_lds K-prefetch, so every
// V use drains the K pipeline — measured 74->138 us in round 6.)
__device__ __forceinline__ void attn_stage(const __bf16* __restrict__ kbase,
                                           const __bf16* __restrict__ vbase,
                                           int l0, int tid,
                                           __bf16* __restrict__ Ksb,
                                           __bf16* __restrict__ Vsb) {
    int c   = tid;                   // 0..511 chunks of 8 bf16
    int row = c >> 3;
    int kc  = (c & 7) ^ (row & 7);   // XOR swizzle
    int cb  = c & ~63;               // wave-uniform chunk base
    gld16(kbase + (size_t)(l0 + row) * EMB + kc * 8, Ksb + cb * 8);
    gld16(vbase + (size_t)row * SLEN + l0 + kc * 8, Vsb + cb * 8);
}

// ---- half-tile (32 keys) building blocks for the rolling pipeline ----
// QK^T + exp2 + RTZ pack for keys [ks*32, ks*32+32) of one 64-key K tile.
// pk[jq][jkl*2+h]: keys 16*(ks*2+jkl) + 4*quad + 2*h + {0,1}, q-col = l16.
__device__ __forceinline__ void qkexp_half(const __bf16* __restrict__ Ksb, int ks,
                                           const bf8_t (*bq)[2],
                                           uint32_t (*pk)[4],
                                           int quad, int l16, int sw) {
#pragma unroll
    for (int jkl = 0; jkl < 2; ++jkl) {
        const int jk = ks * 2 + jkl;
        bf8_t ak0 = *(const bf8_t*)&Ksb[(jk * 16 + l16) * 64 + ((quad ^ sw) * 8)];
        bf8_t ak1 = *(const bf8_t*)&Ksb[(jk * 16 + l16) * 64 + (((4 + quad) ^ sw) * 8)];
#pragma unroll
        for (int jq = 0; jq < 2; ++jq) {
            f4_t e = (f4_t){0.f, 0.f, 0.f, 0.f};
            e = __builtin_amdgcn_mfma_f32_16x16x32_bf16(ak0, bq[jq][0], e, 0, 0, 0);
            e = __builtin_amdgcn_mfma_f32_16x16x32_bf16(ak1, bq[jq][1], e, 0, 0, 0);
            pk[jq][jkl * 2 + 0] = pack_bf16_rtz(EXP2(e[0]), EXP2(e[1]));
            pk[jq][jkl * 2 + 1] = pack_bf16_rtz(EXP2(e[2]), EXP2(e[3]));
        }
    }
}

// permlane quad-exchange -> B-operand fragments, then PV + denominator for the
// same 32-key half. Exchange derivation: see round-2 notes (verified).
__device__ __forceinline__ void pv_half(const __bf16* __restrict__ Vsb, int ks,
                                        const uint32_t (*pk)[4], bf8_t aones,
                                        f4_t* ls, f4_t (*o)[4],
                                        int quad, int l16, int sw) {
    bf8_t bp[2];
#pragma unroll
    for (int jq = 0; jq < 2; ++jq) {
        u32x2 s0 = __builtin_amdgcn_permlane32_swap(pk[jq][0], pk[jq][2], false, false);
        u32x2 s1 = __builtin_amdgcn_permlane32_swap(pk[jq][1], pk[jq][3], false, false);
        u32x2 t0 = __builtin_amdgcn_permlane16_swap(s0[0], s0[1], false, false);
        u32x2 t1 = __builtin_amdgcn_permlane16_swap(s1[0], s1[1], false, false);
        bp[jq] = __builtin_bit_cast(bf8_t, (u32x4){t0[0], t1[0], t0[1], t1[1]});
    }
    __builtin_amdgcn_s_setprio(1);
#pragma unroll
    for (int jq = 0; jq < 2; ++jq)
        ls[jq] = __builtin_amdgcn_mfma_f32_16x16x32_bf16(aones, bp[jq], ls[jq], 0, 0, 0);
#pragma unroll
    for (int jd = 0; jd < 4; ++jd) {
        bf8_t av = *(const bf8_t*)&Vsb[(jd * 16 + l16) * 64 +
                                       (((ks * 4 + quad) ^ sw) * 8)];
#pragma unroll
        for (int jq = 0; jq < 2; ++jq)
            o[jq][jd] = __builtin_amdgcn_mfma_f32_16x16x32_bf16(av, bp[jq],
                                                                o[jq][jd], 0, 0, 0);
    }
    __builtin_amdgcn_s_setprio(0);
}

// one 128-key pair (tiles A,B), rolling 2-stage pipeline over 4 half-tiles:
// QKexp(h+1) is placed adjacent to PV(h) so its QK-MFMAs co-schedule with the
// previous half's exp2/pack/permlane VALU work (ping-pong pkA/pkB, static idx).
__device__ __forceinline__ void attn_pair(const __bf16* __restrict__ Ka,
                                          const __bf16* __restrict__ Kb,
                                          const __bf16* __restrict__ Va,
                                          const __bf16* __restrict__ Vb,
                                          const bf8_t (*bq)[2], bf8_t aones,
                                          f4_t* ls, f4_t (*o)[4],
                                          int quad, int l16, int sw) {
    uint32_t pkA[2][4], pkB[2][4];
    qkexp_half(Ka, 0, bq, pkA, quad, l16, sw);                 // h0 (bubble head)
    qkexp_half(Ka, 1, bq, pkB, quad, l16, sw);                 // h1 QK
    pv_half(Va, 0, pkA, aones, ls, o, quad, l16, sw);          //  ∥ h0 PV
    qkexp_half(Kb, 0, bq, pkA, quad, l16, sw);                 // h2 QK
    pv_half(Va, 1, pkB, aones, ls, o, quad, l16, sw);          //  ∥ h1 PV
    qkexp_half(Kb, 1, bq, pkB, quad, l16, sw);                 // h3 QK
    pv_half(Vb, 0, pkA, aones, ls, o, quad, l16, sw);          //  ∥ h2 PV
    pv_half(Vb, 1, pkB, aones, ls, o, quad, l16, sw);          // h3 PV (bubble tail)
}

// ---------------------------------------------------------------- flash attention (fixed-max softmax)
// grid: (NB*NH, S/256). block 512 = 8 waves; wave w owns 32 q rows (2 x 16).
// blockIdx.x = head -> same-head q-blocks co-locate on one XCD (L2 K/V reuse:
// FETCH 139MB -> 27MB vs round 0).
// Pair-slot double buffering: 2 slots x (K 16KB + V 16KB) = 64 KB LDS,
// ONE barrier per 128 keys. P fully in registers (permlane exchange) with a
// rolling half-tile pipeline. Last iteration PEELED (straight-line hot loop;
// in-loop branches cost -4%, measured round 4).
// Issue-port ~94% saturated (MfmaUtil 44.6 + VALUBusy 49.4, round 5); exp2 is
// the irreducible VALU cost (1/score). Structural floor ~69 us.
__global__ __launch_bounds__(512, 4) void attn_fwd(const __bf16* __restrict__ Q,
                                                   const __bf16* __restrict__ K,
                                                   const __bf16* __restrict__ Vt,
                                                   __bf16* __restrict__ O) {
    __shared__ __bf16 Ks0[64 * 64], Ks1[64 * 64];   // slot0: keys L..L+127
    __shared__ __bf16 Ks2[64 * 64], Ks3[64 * 64];   // slot1: keys L+128..L+255
    __shared__ __bf16 Vs0[64 * 64], Vs1[64 * 64];
    __shared__ __bf16 Vs2[64 * 64], Vs3[64 * 64];

    const int tid  = threadIdx.x;
    const int lane = tid & 63;
    const int w    = tid >> 6;        // 0..7
    const int quad = lane >> 4;
    const int l16  = lane & 15;
    const int nh   = blockIdx.x;
    const int n    = nh >> 4;
    const int h    = nh & 15;
    const int q0   = blockIdx.y * 256 + w * 32;   // this wave's first q row

    // Q fragments (B-operand layout: n=l16 -> q row q0+jq*16+l16, k=quad*8+j -> d)
    // QSCALE*log2(e) already folded into Wq at cast time -> plain loads.
    bf8_t bq[2][2];  // [jq][ks]
#pragma unroll
    for (int jq = 0; jq < 2; ++jq)
#pragma unroll
        for (int ks = 0; ks < 2; ++ks)
            bq[jq][ks] = *(const bf8_t*)(Q + (size_t)(n * SLEN + q0 + jq * 16 + l16) * EMB +
                                         h * HD + ks * 32 + quad * 8);

    bf8_t aones;
#pragma unroll
    for (int t = 0; t < 8; ++t) aones[t] = (__bf16)1.0f;

    f4_t ls[2];     // denominator accumulator (ones-MFMA; all C rows identical per q)
    f4_t o[2][4];   // [jq][jd]; C-tile row = d = jd*16+quad*4+r, col = q = l16
#pragma unroll
    for (int jq = 0; jq < 2; ++jq) {
        ls[jq] = (f4_t){0.f, 0.f, 0.f, 0.f};
#pragma unroll
        for (int jd = 0; jd < 4; ++jd) o[jq][jd] = (f4_t){0.f, 0.f, 0.f, 0.f};
    }

    const __bf16* kbase = K + (size_t)n * SLEN * EMB + h * HD;
    const __bf16* vbase = Vt + (size_t)nh * HD * SLEN;
    const int sw = l16 & 7;  // XOR swizzle key for fragment reads

    // prologue: stage pair 0 into slot0
    attn_stage(kbase, vbase, 0, tid, Ks0, Vs0);
    attn_stage(kbase, vbase, 64, tid, Ks1, Vs1);

    int it = 0;
    for (; it < 14; it += 2) {   // two 128-key pairs per iteration, straight-line
        int L = it * 128;
        __syncthreads();  // drains stage into slot0; all waves done with slot1
        attn_stage(kbase, vbase, L + 128, tid, Ks2, Vs2);
        attn_stage(kbase, vbase, L + 192, tid, Ks3, Vs3);
        attn_pair(Ks0, Ks1, Vs0, Vs1, bq, aones, ls, o, quad, l16, sw);
        __syncthreads();  // drains stage into slot1; all waves done with slot0
        attn_stage(kbase, vbase, L + 256, tid, Ks0, Vs0);
        attn_stage(kbase, vbase, L + 320, tid, Ks1, Vs1);
        attn_pair(Ks2, Ks3, Vs2, Vs3, bq, aones, ls, o, quad, l16, sw);
    }
    // peeled tail: pairs 14 (slot0, already staged) and 15 (staged here)
    {
        int L = it * 128;  // 1792
        __syncthreads();
        attn_stage(kbase, vbase, L + 128, tid, Ks2, Vs2);
        attn_stage(kbase, vbase, L + 192, tid, Ks3, Vs3);
        attn_pair(Ks0, Ks1, Vs0, Vs1, bq, aones, ls, o, quad, l16, sw);
        __syncthreads();
        attn_pair(Ks2, Ks3, Vs2, Vs3, bq, aones, ls, o, quad, l16, sw);
    }

    // epilogue: normalize, RTN pack, store. q row = q0+jq*16+l16, d = jd*16+quad*4+r
#pragma unroll
    for (int jq = 0; jq < 2; ++jq) {
        float inv = 1.0f / ls[jq][0];
#pragma unroll
        for (int jd = 0; jd < 4; ++jd) {
            uint32_t d0 = pack_bf16_rtn(o[jq][jd][0] * inv, o[jq][jd][1] * inv);
            uint32_t d1 = pack_bf16_rtn(o[jq][jd][2] * inv, o[jq][jd][3] * inv);
            *(uint2*)&O[(size_t)(n * SLEN + q0 + jq * 16 + l16) * EMB + h * HD +
                        jd * 16 + quad * 4] = (uint2){d0, d1};
        }
    }
}

// ---------------------------------------------------------------- launch
extern "C" void kernel_launch(void* const* d_in, const int* in_sizes, int n_in,
                              void* d_out, int out_size, void* d_ws, size_t ws_size,
                              hipStream_t stream) {
    const float* x  = (const float*)d_in[0];
    const float* Wq = (const float*)d_in[1];
    const float* Wk = (const float*)d_in[2];
    const float* Wv = (const float*)d_in[3];
    const float* Wo = (const float*)d_in[4];
    const float* bo = (const float*)d_in[5];

    // Workspace layout (72 MB; ab aliases xb — x dead after projections).
    // wqb.. contiguous [Wq|Wk|Wv|Wo] bf16; qb/kb/vtb contiguous at 16MB strides.
    char* wsb = (char*)d_ws;
    const size_t MB = (size_t)1 << 20;
    __bf16* xb  = (__bf16*)(wsb + 0 * MB);    // 16 MB  [8192][1024]
    __bf16* ab  = xb;                         // alias
    __bf16* wqb = (__bf16*)(wsb + 16 * MB);   // 2 MB each, contiguous
    __bf16* wob = (__bf16*)(wsb + 22 * MB);
    __bf16* qb  = (__bf16*)(wsb + 24 * MB);   // 16 MB
    __bf16* kb  = (__bf16*)(wsb + 40 * MB);   // 16 MB
    __bf16* vtb = (__bf16*)(wsb + 56 * MB);   // 16 MB  [nh*64+d][2048]

    cast_all<<<dim3(12288), dim3(256), 0, stream>>>(x, Wq, Wk, Wv, Wo, xb, wqb);

    // fused QKV projection: 1536 blocks (6/CU), dbuf K-loop, DEFAULT 2-D grid
    proj_qkv<<<dim3(MTOT / 128, 3072 / 128), 256, 0, stream>>>(xb, wqb, qb);

    // heads on grid.x -> same-head q-blocks co-locate on one XCD (L2 K/V reuse)
    attn_fwd<<<dim3(NB * NH, SLEN / 256), 512, 0, stream>>>(qb, kb, vtb, ab);

    gemm_out<<<dim3(MTOT / 128, EMB / 128), 256, 0, stream>>>(ab, wob, (float*)d_out, bo);
}